// Round 2
// baseline (418.648 us; speedup 1.0000x reference)
//
#include <hip/hip_runtime.h>
#include <math.h>

#define NHEAD 8
#define TILE 32

// ---------------- K0a: q[j] = (query . W_in[j,:] + b_in[j]) * scale ----------------
__global__ void k_qproj(const float* __restrict__ query, const float* __restrict__ W_in,
                        const float* __restrict__ b_in, float* __restrict__ q_ws,
                        int D, float scale) {
    int j = blockIdx.x * blockDim.x + threadIdx.x;
    if (j >= D) return;
    const float4* wq = reinterpret_cast<const float4*>(W_in + (size_t)j * D);
    const float4* qv = reinterpret_cast<const float4*>(query);
    float acc = 0.f;
    for (int i = 0; i < D / 4; ++i) {
        float4 w = wq[i], q = qv[i];
        acc += w.x * q.x + w.y * q.y + w.z * q.z + w.w * q.w;
    }
    q_ws[j] = (acc + b_in[j]) * scale;
}

// ---------------- K0b: wsc[h*D+i] = sum_d q[h*dh+d] * W_k[(h*dh+d), i] ----------------
__global__ void k_wscore(const float* __restrict__ q_ws, const float* __restrict__ W_in,
                         float* __restrict__ wsc, int D, int dh) {
    int idx = blockIdx.x * blockDim.x + threadIdx.x; // h*D + i
    if (idx >= NHEAD * D) return;
    int h = idx / D, i = idx - h * D;
    const float* Wk = W_in + (size_t)D * D; // rows [D, 2D)
    float acc = 0.f;
    for (int d = 0; d < dh; ++d)
        acc += q_ws[h * dh + d] * Wk[(size_t)(h * dh + d) * D + i];
    wsc[idx] = acc;
}

// ---------------- K1: segment boundaries from sorted batch ids ----------------
__global__ void k_bounds(const int* __restrict__ batch, int* __restrict__ seg_start,
                         int* __restrict__ seg_end, int N) {
    int n = blockIdx.x * blockDim.x + threadIdx.x;
    if (n >= N) return;
    int b = batch[n];
    if (n == 0 || batch[n - 1] != b) seg_start[b] = n;
    if (n == N - 1 || batch[n + 1] != b) seg_end[b] = n + 1;
}

// ---------------- fused: scores + online segment softmax + xp accumulation ----------------
// one block (256 threads) per graph. D==512, H==8.
// per 32-row tile: Phase A thread-per-(row,head) full dot; wave0 does max/sum
// reductions via shfl; all threads own 2 output columns for accumulation.
__global__ void __launch_bounds__(256) k_fused(const float* __restrict__ x,
                                               const float* __restrict__ wsc,
                                               const int* __restrict__ seg_start,
                                               const int* __restrict__ seg_end,
                                               float* __restrict__ xp) {
    const int b = blockIdx.x, t = threadIdx.x;
    __shared__ float sc[TILE][NHEAD];
    __shared__ float pP[TILE][NHEAD];
    __shared__ float mh[NHEAD], lh[NHEAD], fh[NHEAD];
    const int s0 = seg_start[b], s1 = seg_end[b];
    const int rloc = t >> 3, hh = t & 7;
    const float4* wrow = reinterpret_cast<const float4*>(wsc + hh * 512);

    if (t < NHEAD) { mh[t] = -3e38f; lh[t] = 0.f; }
    float acc[16];
#pragma unroll
    for (int i = 0; i < 16; ++i) acc[i] = 0.f;
    __syncthreads();

    for (int base = s0; base < s1; base += TILE) {
        const int lim = min(TILE, s1 - base);

        // Phase A: scores. thread (rloc, hh) computes full 512-dot.
        if (rloc < lim) {
            const float4* xr = reinterpret_cast<const float4*>(x + (size_t)(base + rloc) * 512);
            float d0 = 0.f, d1 = 0.f, d2 = 0.f, d3 = 0.f;
#pragma unroll 4
            for (int i = 0; i < 128; i += 4) {
                float4 xa = xr[i + 0], wa = wrow[i + 0];
                d0 += xa.x * wa.x + xa.y * wa.y + xa.z * wa.z + xa.w * wa.w;
                float4 xb = xr[i + 1], wb = wrow[i + 1];
                d1 += xb.x * wb.x + xb.y * wb.y + xb.z * wb.z + xb.w * wb.w;
                float4 xc = xr[i + 2], wc = wrow[i + 2];
                d2 += xc.x * wc.x + xc.y * wc.y + xc.z * wc.z + xc.w * wc.w;
                float4 xd = xr[i + 3], wd = wrow[i + 3];
                d3 += xd.x * wd.x + xd.y * wd.y + xd.z * wd.z + xd.w * wd.w;
            }
            sc[rloc][hh] = (d0 + d1) + (d2 + d3);
        }
        __syncthreads();

        // wave0: tile max per head -> update running max, rescale factor
        if (t < 64) {
            const int q = t >> 3, h = t & 7;
            float m = -3e38f;
#pragma unroll
            for (int j = 0; j < 4; ++j) {
                int r = q * 4 + j;
                if (r < lim) m = fmaxf(m, sc[r][h]);
            }
            m = fmaxf(m, __shfl_xor(m, 8, 64));
            m = fmaxf(m, __shfl_xor(m, 16, 64));
            m = fmaxf(m, __shfl_xor(m, 32, 64));
            if (t < NHEAD) {
                float mo = mh[t];
                float mn = fmaxf(mo, m);
                mh[t] = mn;
                fh[t] = __expf(mo - mn); // first tile: exp(-inf)=0
            }
        }
        __syncthreads();

        // p-tilde
        pP[rloc][hh] = (rloc < lim) ? __expf(sc[rloc][hh] - mh[hh]) : 0.f;
        __syncthreads();

        // wave0: tile sum per head, update l  (runs ahead of its Phase C work)
        if (t < 64) {
            const int q = t >> 3, h = t & 7;
            float s = pP[q * 4 + 0][h] + pP[q * 4 + 1][h] + pP[q * 4 + 2][h] + pP[q * 4 + 3][h];
            s += __shfl_xor(s, 8, 64);
            s += __shfl_xor(s, 16, 64);
            s += __shfl_xor(s, 32, 64);
            if (t < NHEAD) lh[t] = lh[t] * fh[t] + s;
        }

        // Phase C: rescale accumulators, accumulate p~ * x. thread owns cols 2t,2t+1.
#pragma unroll
        for (int h = 0; h < NHEAD; ++h) {
            float f = fh[h];
            acc[h * 2] *= f;
            acc[h * 2 + 1] *= f;
        }
        const float* xc = x + (size_t)base * 512 + t * 2;
        for (int r = 0; r < lim; ++r) {
            float2 xv = *reinterpret_cast<const float2*>(xc + (size_t)r * 512);
            float4 p0 = *reinterpret_cast<const float4*>(&pP[r][0]);
            float4 p1 = *reinterpret_cast<const float4*>(&pP[r][4]);
            acc[0]  += p0.x * xv.x; acc[1]  += p0.x * xv.y;
            acc[2]  += p0.y * xv.x; acc[3]  += p0.y * xv.y;
            acc[4]  += p0.z * xv.x; acc[5]  += p0.z * xv.y;
            acc[6]  += p0.w * xv.x; acc[7]  += p0.w * xv.y;
            acc[8]  += p1.x * xv.x; acc[9]  += p1.x * xv.y;
            acc[10] += p1.y * xv.x; acc[11] += p1.y * xv.y;
            acc[12] += p1.z * xv.x; acc[13] += p1.z * xv.y;
            acc[14] += p1.w * xv.x; acc[15] += p1.w * xv.y;
        }
        __syncthreads();
    }

    // epilogue: normalize by l, write xp[b][h][2t..2t+1]
    float* xpb = xp + (size_t)b * NHEAD * 512 + t * 2;
#pragma unroll
    for (int h = 0; h < NHEAD; ++h) {
        float rl = 1.f / lh[h];
        float2 o;
        o.x = acc[h * 2] * rl;
        o.y = acc[h * 2 + 1] * rl;
        *reinterpret_cast<float2*>(xpb + h * 512) = o;
    }
}

// ---------------- tiled f32 GEMM: C[m,n] = sum_k A[m,k]*B[n,k] + bias[n] ----------------
// 64 threads (1 wave), 32x32 tile, 4x4 microtile. LDS stored k-major ([kk][m], pad 36)
// so compute reads are conflict-free ds_read_b128.
__global__ void __launch_bounds__(64) k_gemm_tn4(const float* __restrict__ A, int lda, int zA,
                                                 const float* __restrict__ Bm, int ldb, int zB,
                                                 const float* __restrict__ bias, int zBias,
                                                 float* __restrict__ C, int ldc, int zC, int K) {
    __shared__ float As[32][36]; // [kk][m]
    __shared__ float Bs[32][36]; // [kk][n]
    const int z = blockIdx.z;
    A += (size_t)z * zA;
    Bm += (size_t)z * zB;
    bias += (size_t)z * zBias;
    C += (size_t)z * zC;
    const int m0 = blockIdx.x * 32, n0 = blockIdx.y * 32;
    const int t = threadIdx.x;
    const int row = t >> 1, c0 = (t & 1) * 16;
    const int ty = t >> 3, tx = t & 7;
    float c[4][4];
#pragma unroll
    for (int i = 0; i < 4; ++i)
#pragma unroll
        for (int j = 0; j < 4; ++j) c[i][j] = 0.f;

    for (int k0 = 0; k0 < K; k0 += 32) {
        float4 a4[4], b4[4];
        const float* Ar = A + (size_t)(m0 + row) * lda + k0 + c0;
        const float* Br = Bm + (size_t)(n0 + row) * ldb + k0 + c0;
#pragma unroll
        for (int j = 0; j < 4; ++j) {
            a4[j] = *reinterpret_cast<const float4*>(Ar + j * 4);
            b4[j] = *reinterpret_cast<const float4*>(Br + j * 4);
        }
        __syncthreads(); // previous iteration's compute reads done
#pragma unroll
        for (int j = 0; j < 4; ++j) {
            As[c0 + j * 4 + 0][row] = a4[j].x;
            As[c0 + j * 4 + 1][row] = a4[j].y;
            As[c0 + j * 4 + 2][row] = a4[j].z;
            As[c0 + j * 4 + 3][row] = a4[j].w;
            Bs[c0 + j * 4 + 0][row] = b4[j].x;
            Bs[c0 + j * 4 + 1][row] = b4[j].y;
            Bs[c0 + j * 4 + 2][row] = b4[j].z;
            Bs[c0 + j * 4 + 3][row] = b4[j].w;
        }
        __syncthreads();
#pragma unroll
        for (int kk = 0; kk < 32; ++kk) {
            float4 av = *reinterpret_cast<const float4*>(&As[kk][ty * 4]);
            float4 bv = *reinterpret_cast<const float4*>(&Bs[kk][tx * 4]);
            c[0][0] += av.x * bv.x; c[0][1] += av.x * bv.y; c[0][2] += av.x * bv.z; c[0][3] += av.x * bv.w;
            c[1][0] += av.y * bv.x; c[1][1] += av.y * bv.y; c[1][2] += av.y * bv.z; c[1][3] += av.y * bv.w;
            c[2][0] += av.z * bv.x; c[2][1] += av.z * bv.y; c[2][2] += av.z * bv.z; c[2][3] += av.z * bv.w;
            c[3][0] += av.w * bv.x; c[3][1] += av.w * bv.y; c[3][2] += av.w * bv.z; c[3][3] += av.w * bv.w;
        }
    }
    const int mr = m0 + ty * 4, nc = n0 + tx * 4;
    float4 bv4 = *reinterpret_cast<const float4*>(bias + nc);
#pragma unroll
    for (int i = 0; i < 4; ++i) {
        float4 o;
        o.x = c[i][0] + bv4.x;
        o.y = c[i][1] + bv4.y;
        o.z = c[i][2] + bv4.z;
        o.w = c[i][3] + bv4.w;
        *reinterpret_cast<float4*>(C + (size_t)(mr + i) * ldc + nc) = o;
    }
}

extern "C" void kernel_launch(void* const* d_in, const int* in_sizes, int n_in,
                              void* d_out, int out_size, void* d_ws, size_t ws_size,
                              hipStream_t stream) {
    const float* x     = (const float*)d_in[0];
    const int*   batch = (const int*)d_in[1];
    // d_in[2] = num_graphs scalar (derived from out_size instead)
    const float* query = (const float*)d_in[3];
    const float* W_in  = (const float*)d_in[4];
    const float* b_in  = (const float*)d_in[5];
    const float* W_out = (const float*)d_in[6];
    const float* b_out = (const float*)d_in[7];
    float* out = (float*)d_out;

    const int D = in_sizes[3];         // 512
    const int N = in_sizes[0] / D;     // 131072
    const int B = out_size / D;        // 512 graphs
    const int dh = D / NHEAD;          // 64
    const float scale = 1.0f / sqrtf((float)dh);

    // workspace carve (floats)
    float* wsf     = (float*)d_ws;
    float* q_ws    = wsf;                                 // D
    float* wsc     = wsf + 512;                           // H*D
    float* xp      = wsc + NHEAD * 512;                   // B*H*D
    float* pooled  = xp + (size_t)B * NHEAD * 512;        // B*D
    int*   seg_start = (int*)(pooled + (size_t)B * 512);  // B
    int*   seg_end   = seg_start + B;                     // B

    // K0: q projection + score-weight folding
    k_qproj<<<(D + 255) / 256, 256, 0, stream>>>(query, W_in, b_in, q_ws, D, scale);
    k_wscore<<<(NHEAD * D + 255) / 256, 256, 0, stream>>>(q_ws, W_in, wsc, D, dh);

    // K1: segment bounds
    k_bounds<<<(N + 255) / 256, 256, 0, stream>>>(batch, seg_start, seg_end, N);

    // K2: fused scores + online softmax + weighted x accumulation
    k_fused<<<B, 256, 0, stream>>>(x, wsc, seg_start, seg_end, xp);

    // K4: pooled[b, h*64+j] = sum_i xp[b,h,i] * W_v[h*64+j, i] + b_v[h*64+j]
    k_gemm_tn4<<<dim3(B / 32, dh / 32, NHEAD), 64, 0, stream>>>(
        xp, NHEAD * 512, 512,
        W_in + (size_t)2 * D * D, D, dh * D,
        b_in + 2 * D, dh,
        pooled, D, dh, D);

    // K5: out = pooled @ W_out^T + b_out
    k_gemm_tn4<<<dim3(B / 32, D / 32, 1), 64, 0, stream>>>(
        pooled, D, 0,
        W_out, D, 0,
        b_out, 0,
        out, D, 0, D);
}

// Round 3
// 214.050 us; speedup vs baseline: 1.9558x; 1.9558x over previous
//
#include <hip/hip_runtime.h>
#include <math.h>

#define NHEAD 8

// ---------------- K0a: q[j] = (query . W_in[j,:] + b_in[j]) * scale ----------------
__global__ void k_qproj(const float* __restrict__ query, const float* __restrict__ W_in,
                        const float* __restrict__ b_in, float* __restrict__ q_ws,
                        int D, float scale) {
    int j = blockIdx.x * blockDim.x + threadIdx.x;
    if (j >= D) return;
    const float4* wq = reinterpret_cast<const float4*>(W_in + (size_t)j * D);
    const float4* qv = reinterpret_cast<const float4*>(query);
    float acc = 0.f;
    for (int i = 0; i < D / 4; ++i) {
        float4 w = wq[i], q = qv[i];
        acc += w.x * q.x + w.y * q.y + w.z * q.z + w.w * q.w;
    }
    q_ws[j] = (acc + b_in[j]) * scale;
}

// ---------------- K0b: wsc[h*D+i] = sum_d q[h*dh+d] * W_k[(h*dh+d), i] ----------------
__global__ void k_wscore(const float* __restrict__ q_ws, const float* __restrict__ W_in,
                         float* __restrict__ wsc, int D, int dh) {
    int idx = blockIdx.x * blockDim.x + threadIdx.x; // h*D + i
    if (idx >= NHEAD * D) return;
    int h = idx / D, i = idx - h * D;
    const float* Wk = W_in + (size_t)D * D; // rows [D, 2D)
    float acc = 0.f;
    for (int d = 0; d < dh; ++d)
        acc += q_ws[h * dh + d] * Wk[(size_t)(h * dh + d) * D + i];
    wsc[idx] = acc;
}

// ---------------- K1: segment boundaries from sorted batch ids ----------------
__global__ void k_bounds(const int* __restrict__ batch, int* __restrict__ seg_start,
                         int* __restrict__ seg_end, int N) {
    int n = blockIdx.x * blockDim.x + threadIdx.x;
    if (n >= N) return;
    int b = batch[n];
    if (n == 0 || batch[n - 1] != b) seg_start[b] = n;
    if (n == N - 1 || batch[n + 1] != b) seg_end[b] = n + 1;
}

// ---------------- K2: scores[n,h] = x[n,:] . wsc[h,:]   (D==512, wave per row) ----------------
__global__ void __launch_bounds__(256) k_scores(const float* __restrict__ x,
                                                const float* __restrict__ wsc,
                                                float* __restrict__ scores, int N) {
    const int t = threadIdx.x, lane = t & 63, wid = t >> 6;
    const int gw = blockIdx.x * 4 + wid;
    float4 w0[NHEAD], w1[NHEAD];
#pragma unroll
    for (int h = 0; h < NHEAD; ++h) {
        w0[h] = *reinterpret_cast<const float4*>(wsc + h * 512 + lane * 8);
        w1[h] = *reinterpret_cast<const float4*>(wsc + h * 512 + lane * 8 + 4);
    }
    const int base = gw * 16;
    for (int r = 0; r < 16; ++r) {
        int row = base + r;
        if (row >= N) return;
        const float* xr = x + (size_t)row * 512 + lane * 8;
        float4 xa = *reinterpret_cast<const float4*>(xr);
        float4 xb = *reinterpret_cast<const float4*>(xr + 4);
        float acc[NHEAD];
#pragma unroll
        for (int h = 0; h < NHEAD; ++h) {
            acc[h] = xa.x * w0[h].x + xa.y * w0[h].y + xa.z * w0[h].z + xa.w * w0[h].w +
                     xb.x * w1[h].x + xb.y * w1[h].y + xb.z * w1[h].z + xb.w * w1[h].w;
        }
#pragma unroll
        for (int h = 0; h < NHEAD; ++h) {
#pragma unroll
            for (int off = 1; off < 64; off <<= 1)
                acc[h] += __shfl_xor(acc[h], off, 64);
        }
        if (lane == 0) {
            float4 s0 = {acc[0], acc[1], acc[2], acc[3]};
            float4 s1 = {acc[4], acc[5], acc[6], acc[7]};
            float4* sp = reinterpret_cast<float4*>(scores + (size_t)row * 8);
            sp[0] = s0;
            sp[1] = s1;
        }
    }
}

// ---------------- K2b: per-graph per-head max + reciprocal softmax denominator ----------------
__global__ void __launch_bounds__(256) k_segstat(const float* __restrict__ scores,
                                                 const int* __restrict__ seg_start,
                                                 const int* __restrict__ seg_end,
                                                 float* __restrict__ m_out,
                                                 float* __restrict__ rd_out) {
    const int b = blockIdx.x, t = threadIdx.x;
    __shared__ float part[256];
    __shared__ float mxs[NHEAD];
    const int s0 = seg_start[b], s1 = seg_end[b];
    const int h = t & 7, nl = t >> 3;
    float m = -3e38f;
    for (int n = s0 + nl; n < s1; n += 32) m = fmaxf(m, scores[(size_t)n * 8 + h]);
    part[t] = m;
    __syncthreads();
    if (t < NHEAD) {
        float mm = part[t];
        for (int g = 1; g < 32; ++g) mm = fmaxf(mm, part[g * 8 + t]);
        mxs[t] = mm;
        m_out[b * NHEAD + t] = mm;
    }
    __syncthreads();
    const float mh = mxs[h];
    float s = 0.f;
    for (int n = s0 + nl; n < s1; n += 32) s += __expf(scores[(size_t)n * 8 + h] - mh);
    __syncthreads(); // part reuse
    part[t] = s;
    __syncthreads();
    if (t < NHEAD) {
        float ss = 0.f;
        for (int g = 0; g < 32; ++g) ss += part[g * 8 + t];
        rd_out[b * NHEAD + t] = 1.f / ss;
    }
}

// ---------------- K3: xp[b,h,c] = sum_n p[n,h] * x[n,c]  (column-split) ----------------
// grid (B, 4): block owns graph b, columns [cc0, cc0+128). 256 threads:
// rg = t>>5 (row-group 0..7), cl = t&31 (4 cols each).
__global__ void __launch_bounds__(256) k_xp(const float* __restrict__ x,
                                            const float* __restrict__ scores,
                                            const int* __restrict__ seg_start,
                                            const int* __restrict__ seg_end,
                                            const float* __restrict__ m_in,
                                            const float* __restrict__ rd_in,
                                            float* __restrict__ xp) {
    const int b = blockIdx.x;
    const int cc0 = blockIdx.y * 128;
    const int t = threadIdx.x;
    const int cl = t & 31, rg = t >> 5;
    const int hh = t & 7;
    __shared__ float p_lds[64][NHEAD];
    __shared__ float red[256][32];
    const int s0 = seg_start[b], s1 = seg_end[b];
    const float mh = m_in[b * NHEAD + hh];
    const float rdh = rd_in[b * NHEAD + hh];

    float acc[NHEAD][4];
#pragma unroll
    for (int h = 0; h < NHEAD; ++h)
#pragma unroll
        for (int j = 0; j < 4; ++j) acc[h][j] = 0.f;

    for (int tbase = s0; tbase < s1; tbase += 64) {
        const int lim = min(64, s1 - tbase);
        // stage p for this 64-row tile (coalesced scores read: flat = tbase*8 + t)
        {
            const int r0 = t >> 3;
            p_lds[r0][hh] = (r0 < lim) ? __expf(scores[(size_t)(tbase + r0) * 8 + hh] - mh) * rdh : 0.f;
            const int r1 = r0 + 32;
            p_lds[r1][hh] = (r1 < lim) ? __expf(scores[(size_t)(tbase + r1) * 8 + hh] - mh) * rdh : 0.f;
        }
        __syncthreads();
        for (int r = rg; r < lim; r += 8) {
            const float4 xv = *reinterpret_cast<const float4*>(x + (size_t)(tbase + r) * 512 + cc0 + cl * 4);
            const float4 p0 = *reinterpret_cast<const float4*>(&p_lds[r][0]);
            const float4 p1 = *reinterpret_cast<const float4*>(&p_lds[r][4]);
            const float pp[8] = {p0.x, p0.y, p0.z, p0.w, p1.x, p1.y, p1.z, p1.w};
#pragma unroll
            for (int h = 0; h < NHEAD; ++h) {
                acc[h][0] += pp[h] * xv.x;
                acc[h][1] += pp[h] * xv.y;
                acc[h][2] += pp[h] * xv.z;
                acc[h][3] += pp[h] * xv.w;
            }
        }
        __syncthreads();
    }

    // cross-rowgroup reduction
#pragma unroll
    for (int h = 0; h < NHEAD; ++h)
#pragma unroll
        for (int j = 0; j < 4; ++j) red[t][h * 4 + j] = acc[h][j];
    __syncthreads();
    const int ho = t >> 5, co = (t & 31) * 4;
    float4 s = {0.f, 0.f, 0.f, 0.f};
#pragma unroll
    for (int g = 0; g < 8; ++g) {
        const float4 v = *reinterpret_cast<const float4*>(&red[g * 32 + (t & 31)][ho * 4]);
        s.x += v.x; s.y += v.y; s.z += v.z; s.w += v.w;
    }
    *reinterpret_cast<float4*>(xp + (size_t)b * NHEAD * 512 + (size_t)ho * 512 + cc0 + co) = s;
}

// ---------------- 4-wave K-split GEMM: C[m,n] = sum_k A[m,k]*B[n,k] + bias[n] ----------------
// 32x32 tile, 256 threads = 4 waves; wave w covers k in [w*K/4,(w+1)*K/4).
// Each wave has a PRIVATE LDS region -> no barriers in the main loop.
__global__ void __launch_bounds__(256) k_gemm_tn4w(const float* __restrict__ A, int lda, int zA,
                                                   const float* __restrict__ Bm, int ldb, int zB,
                                                   const float* __restrict__ bias, int zBias,
                                                   float* __restrict__ C, int ldc, int zC, int K) {
    __shared__ float As[4][32][36]; // [wave][kk][m]
    __shared__ float Bs[4][32][36]; // [wave][kk][n]
    __shared__ float red[4][32][32];
    const int z = blockIdx.z;
    A += (size_t)z * zA;
    Bm += (size_t)z * zB;
    bias += (size_t)z * zBias;
    C += (size_t)z * zC;
    const int m0 = blockIdx.x * 32, n0 = blockIdx.y * 32;
    const int t = threadIdx.x;
    const int w = t >> 6, lane = t & 63;
    const int row = lane >> 1, c0 = (lane & 1) * 16;
    const int ty = lane >> 3, tx = lane & 7;
    const int Kw = K >> 2;
    const int kw0 = w * Kw;
    float c[4][4];
#pragma unroll
    for (int i = 0; i < 4; ++i)
#pragma unroll
        for (int j = 0; j < 4; ++j) c[i][j] = 0.f;

    for (int kt = 0; kt < Kw; kt += 32) {
        const int k0 = kw0 + kt;
        const float* Ar = A + (size_t)(m0 + row) * lda + k0 + c0;
        const float* Br = Bm + (size_t)(n0 + row) * ldb + k0 + c0;
        float4 a4[4], b4[4];
#pragma unroll
        for (int j = 0; j < 4; ++j) {
            a4[j] = *reinterpret_cast<const float4*>(Ar + j * 4);
            b4[j] = *reinterpret_cast<const float4*>(Br + j * 4);
        }
#pragma unroll
        for (int j = 0; j < 4; ++j) {
            As[w][c0 + j * 4 + 0][row] = a4[j].x;
            As[w][c0 + j * 4 + 1][row] = a4[j].y;
            As[w][c0 + j * 4 + 2][row] = a4[j].z;
            As[w][c0 + j * 4 + 3][row] = a4[j].w;
            Bs[w][c0 + j * 4 + 0][row] = b4[j].x;
            Bs[w][c0 + j * 4 + 1][row] = b4[j].y;
            Bs[w][c0 + j * 4 + 2][row] = b4[j].z;
            Bs[w][c0 + j * 4 + 3][row] = b4[j].w;
        }
        // same-wave LDS RAW: compiler inserts lgkmcnt waits; no block barrier needed
#pragma unroll
        for (int kk = 0; kk < 32; ++kk) {
            float4 av = *reinterpret_cast<const float4*>(&As[w][kk][ty * 4]);
            float4 bv = *reinterpret_cast<const float4*>(&Bs[w][kk][tx * 4]);
            c[0][0] += av.x * bv.x; c[0][1] += av.x * bv.y; c[0][2] += av.x * bv.z; c[0][3] += av.x * bv.w;
            c[1][0] += av.y * bv.x; c[1][1] += av.y * bv.y; c[1][2] += av.y * bv.z; c[1][3] += av.y * bv.w;
            c[2][0] += av.z * bv.x; c[2][1] += av.z * bv.y; c[2][2] += av.z * bv.z; c[2][3] += av.z * bv.w;
            c[3][0] += av.w * bv.x; c[3][1] += av.w * bv.y; c[3][2] += av.w * bv.z; c[3][3] += av.w * bv.w;
        }
    }
    // stash partial tile
#pragma unroll
    for (int i = 0; i < 4; ++i)
#pragma unroll
        for (int j = 0; j < 4; ++j) red[w][ty * 4 + i][tx * 4 + j] = c[i][j];
    __syncthreads();
    // merge 4 wave-partials: thread t handles row r=t>>3, cols cc..cc+3
    const int r = t >> 3, cc = (t & 7) * 4;
    float4 s = {0.f, 0.f, 0.f, 0.f};
#pragma unroll
    for (int g = 0; g < 4; ++g) {
        const float4 v = *reinterpret_cast<const float4*>(&red[g][r][cc]);
        s.x += v.x; s.y += v.y; s.z += v.z; s.w += v.w;
    }
    const float4 bv4 = *reinterpret_cast<const float4*>(bias + n0 + cc);
    float4 o = {s.x + bv4.x, s.y + bv4.y, s.z + bv4.z, s.w + bv4.w};
    *reinterpret_cast<float4*>(C + (size_t)(m0 + r) * ldc + n0 + cc) = o;
}

extern "C" void kernel_launch(void* const* d_in, const int* in_sizes, int n_in,
                              void* d_out, int out_size, void* d_ws, size_t ws_size,
                              hipStream_t stream) {
    const float* x     = (const float*)d_in[0];
    const int*   batch = (const int*)d_in[1];
    // d_in[2] = num_graphs scalar (derived from out_size instead)
    const float* query = (const float*)d_in[3];
    const float* W_in  = (const float*)d_in[4];
    const float* b_in  = (const float*)d_in[5];
    const float* W_out = (const float*)d_in[6];
    const float* b_out = (const float*)d_in[7];
    float* out = (float*)d_out;

    const int D = in_sizes[3];         // 512
    const int N = in_sizes[0] / D;     // 131072
    const int B = out_size / D;        // 512 graphs
    const int dh = D / NHEAD;          // 64
    const float scale = 1.0f / sqrtf((float)dh);

    // workspace carve (floats)
    float* wsf     = (float*)d_ws;
    float* q_ws    = wsf;                                 // D
    float* wsc     = wsf + 512;                           // H*D
    float* scores  = wsc + NHEAD * 512;                   // N*H
    float* m_ws    = scores + (size_t)N * NHEAD;          // B*H
    float* rd_ws   = m_ws + (size_t)B * NHEAD;            // B*H
    float* xp      = rd_ws + (size_t)B * NHEAD;           // B*H*D
    float* pooled  = xp + (size_t)B * NHEAD * 512;        // B*D
    int*   seg_start = (int*)(pooled + (size_t)B * 512);  // B
    int*   seg_end   = seg_start + B;                     // B

    // K0: q projection + score-weight folding
    k_qproj<<<(D + 255) / 256, 256, 0, stream>>>(query, W_in, b_in, q_ws, D, scale);
    k_wscore<<<(NHEAD * D + 255) / 256, 256, 0, stream>>>(q_ws, W_in, wsc, D, dh);

    // K1: segment bounds
    k_bounds<<<(N + 255) / 256, 256, 0, stream>>>(batch, seg_start, seg_end, N);

    // K2: scores = x @ wsc^T
    int waves = (N + 15) / 16;
    k_scores<<<(waves + 3) / 4, 256, 0, stream>>>(x, wsc, scores, N);

    // K2b: per-graph softmax stats
    k_segstat<<<B, 256, 0, stream>>>(scores, seg_start, seg_end, m_ws, rd_ws);

    // K3: weighted accumulation, column-split
    k_xp<<<dim3(B, 4), 256, 0, stream>>>(x, scores, seg_start, seg_end, m_ws, rd_ws, xp);

    // K4: pooled[b, h*64+j] = sum_i xp[b,h,i] * W_v[h*64+j, i] + b_v[h*64+j]
    k_gemm_tn4w<<<dim3(B / 32, dh / 32, NHEAD), 256, 0, stream>>>(
        xp, NHEAD * 512, 512,
        W_in + (size_t)2 * D * D, D, dh * D,
        b_in + 2 * D, dh,
        pooled, D, dh, D);

    // K5: out = pooled @ W_out^T + b_out
    k_gemm_tn4w<<<dim3(B / 32, D / 32, 1), 256, 0, stream>>>(
        pooled, D, 0,
        W_out, D, 0,
        b_out, 0,
        out, D, 0, D);
}